// Round 6
// baseline (442.247 us; speedup 1.0000x reference)
//
#include <hip/hip_runtime.h>
#include <hip/hip_bf16.h>

#define D 256
#define NC 512
#define NROWS 131072L

// out layout (fp32 elements), reference return order
#define OFF_ZQ   0L
#define OFF_VQ   33554432L
#define OFF_CM   33554433L
#define OFF_IDX  33554434L
#define OFF_HIST 33685506L

// ws float offsets
#define WS_LPART 0        // [0, 2048)       per-block loss partials
#define WS_HIST  2048     // [2048, 2560)
#define WS_E2    2560     // [2560, 3072)
#define WS_CNT   3072     // ambig count (int)
#define WS_DONE  3073     // hist done-counter (int)
#define WS_AMB   3136     // [3136, 134208)   ambig row list (int)
#define WS_FIDX  134208   // [134208, 265280) final idx (int)
#define WS_BK    265280   // bf16 eh, k-slab-major: 8 slabs x 512 codes x 32 k
#define WS_NEED  (330816L * 4)

#define MARGIN 0.75f

typedef __attribute__((ext_vector_type(8))) short bf16x8;
typedef __attribute__((ext_vector_type(4))) float f32x4;

__device__ __forceinline__ unsigned short f2bf(float f) {
    union { float f; unsigned int u; } a; a.f = f;
    return (unsigned short)((a.u + 0x7FFFu + ((a.u >> 16) & 1u)) >> 16);  // RNE
}

// kept for fallback path
__global__ void vq_e2(const float* __restrict__ e, float* __restrict__ e2) {
    int c = blockIdx.x;
    int l = threadIdx.x;  // 64
    float4 v = *(const float4*)(e + c * D + l * 4);
    float s = v.x * v.x + v.y * v.y + v.z * v.z + v.w * v.w;
    #pragma unroll
    for (int off = 32; off; off >>= 1) s += __shfl_xor(s, off);
    if (l == 0) e2[c] = s;
}

// Bk[slab][code][32] = bf16(e[code][slab*32..+32)) + fused e2 + ws zeroing
__global__ void vq_convB(const float* __restrict__ e, unsigned short* __restrict__ Bk,
                         float* __restrict__ e2, float* __restrict__ hist,
                         int* __restrict__ acnt, int* __restrict__ done) {
    __shared__ float r4[4];
    int code = blockIdx.x, k = threadIdx.x;   // 512 blocks x 256 threads
    float v = e[code * D + k];
    Bk[((k >> 5) * NC + code) * 32 + (k & 31)] = f2bf(v);
    float s = v * v;
    #pragma unroll
    for (int off = 32; off; off >>= 1) s += __shfl_xor(s, off);
    if ((k & 63) == 0) r4[k >> 6] = s;
    if (k == 0) {
        hist[code] = 0.0f;                    // zero hist bin owned by this block
        if (code == 0) { *acnt = 0; *done = 0; }
    }
    __syncthreads();
    if (k == 0) e2[code] = r4[0] + r4[1] + r4[2] + r4[3];
}

// NO-LDS GEMM. 64x512 block tile, 8 waves as 2(M)x4(N): wave owns 32 rows x 128
// cols. A-panel (16 bf16x8 = 64 VGPR) built ONCE from global; B streams via a
// 4-deep register ring over 64 flattened (nt,s) iterations; per-lane online
// top-2 (8 rows). Zero LDS ops and zero barriers in the hot path.
__global__ __launch_bounds__(512, 3)
void vq_gemm(const float* __restrict__ z, const unsigned short* __restrict__ Bk,
             const float* __restrict__ e2, int* __restrict__ fidx,
             int* __restrict__ acnt, int* __restrict__ alist) {
    __shared__ float red[64 * 13];   // 3.3 KB merge buffer (stride 13: odd)

    const int tid = threadIdx.x;
    const int w = tid >> 6, l = tid & 63, q = l >> 4, ln = l & 15;
    const int wm = w >> 2, wn = w & 3;
    const long row0 = (long)blockIdx.x * 64;
    const long rowW = row0 + wm * 32;

    // ---- A fragments in registers: af[mt][s], lane(q,ln) holds
    //      z[rowW+mt*16+ln][s*32 + q*8 .. +8] as bf16 ----
    bf16x8 af[2][8];
    #pragma unroll
    for (int mt = 0; mt < 2; ++mt) {
        const float* zp = z + (rowW + mt * 16 + ln) * D + q * 8;
        #pragma unroll
        for (int s = 0; s < 8; ++s) {
            float4 a0 = *(const float4*)(zp + s * 32);
            float4 a1 = *(const float4*)(zp + s * 32 + 4);
            bf16x8 t;
            t[0] = (short)f2bf(a0.x); t[1] = (short)f2bf(a0.y);
            t[2] = (short)f2bf(a0.z); t[3] = (short)f2bf(a0.w);
            t[4] = (short)f2bf(a1.x); t[5] = (short)f2bf(a1.y);
            t[6] = (short)f2bf(a1.z); t[7] = (short)f2bf(a1.w);
            af[mt][s] = t;
        }
    }

    float e2v[8];
    #pragma unroll
    for (int nt = 0; nt < 8; ++nt) e2v[nt] = e2[wn * 128 + nt * 16 + ln];

    // ---- B ring: iteration it = nt*8 + s over the wave's 128-col slice ----
    const unsigned short* bb = Bk + ((wn * 128 + ln) * 32 + q * 8);
    bf16x8 ring[4];
    #pragma unroll
    for (int p = 0; p < 4; ++p)    // p < 8 => nt = 0 slab p
        ring[p] = *(const bf16x8*)(bb + (p & 7) * (NC * 32) + (p >> 3) * (16 * 32));

    float v1[8], v2[8]; int i1[8];  // tracked rows k = mt*4 + r
    #pragma unroll
    for (int k = 0; k < 8; ++k) { v1[k] = -3.0e38f; v2[k] = -3.0e38f; i1[k] = 0; }

    #pragma unroll
    for (int nt = 0; nt < 8; ++nt) {
        f32x4 acc0 = (f32x4){0.f, 0.f, 0.f, 0.f};
        f32x4 acc1 = (f32x4){0.f, 0.f, 0.f, 0.f};
        #pragma unroll
        for (int s = 0; s < 8; ++s) {
            const int it = nt * 8 + s;
            bf16x8 b = ring[it & 3];
            if (it + 4 < 64) {              // compile-time folded (fully unrolled)
                const int jt = it + 4;
                ring[it & 3] = *(const bf16x8*)(bb + (jt & 7) * (NC * 32) + (jt >> 3) * (16 * 32));
            }
            acc0 = __builtin_amdgcn_mfma_f32_16x16x32_bf16(af[0][s], b, acc0, 0, 0, 0);
            acc1 = __builtin_amdgcn_mfma_f32_16x16x32_bf16(af[1][s], b, acc1, 0, 0, 0);
        }
        const int colc = wn * 128 + nt * 16 + ln;
        #pragma unroll
        for (int r = 0; r < 4; ++r) {
            float v = fmaf(-2.0f, acc0[r], e2v[nt]);
            if (v > v1[r]) { v2[r] = v1[r]; v1[r] = v; i1[r] = colc; }
            else v2[r] = fmaxf(v2[r], v);
            float u = fmaf(-2.0f, acc1[r], e2v[nt]);
            if (u > v1[4 + r]) { v2[4 + r] = v1[4 + r]; v1[4 + r] = u; i1[4 + r] = colc; }
            else v2[4 + r] = fmaxf(v2[4 + r], u);
        }
    }

    // ---- 16-lane butterfly per tracked row (value-only; ties => ambiguous) ----
    #pragma unroll
    for (int k = 0; k < 8; ++k) {
        float v1p = v1[k];
        #pragma unroll
        for (int off = 1; off < 16; off <<= 1) {
            float o1 = __shfl_xor(v1[k], off);
            float o2 = __shfl_xor(v2[k], off);
            v2[k] = fmaxf(fmaxf(v2[k], o2), fminf(v1[k], o1));
            v1[k] = fmaxf(v1[k], o1);
        }
        unsigned long long mm = __ballot(v1p == v1[k]);
        unsigned int gm = (unsigned int)((mm >> (q * 16)) & 0xFFFFULL);
        int src = (q << 4) + (__ffs(gm) - 1);
        int ii = __shfl(i1[k], src);
        if (ln == 0) {
            const int mt = k >> 2, r = k & 3;
            const int rr = wm * 32 + mt * 16 + q * 4 + r;   // block-local row
            red[rr * 13 + wn * 3 + 0] = v1[k];
            red[rr * 13 + wn * 3 + 1] = (float)ii;
            red[rr * 13 + wn * 3 + 2] = v2[k];
        }
    }
    __syncthreads();
    // ---- 4-way col-group merge; wave-aggregated ambiguous append ----
    if (tid < 64) {
        float v1m = -3.0e38f, v2m = -3.0e38f; int i1m = 0;
        #pragma unroll
        for (int g = 0; g < 4; ++g) {
            float rv1 = red[tid * 13 + g * 3 + 0];
            int   ri  = (int)red[tid * 13 + g * 3 + 1];
            float rv2 = red[tid * 13 + g * 3 + 2];
            if (rv1 > v1m) { v2m = fmaxf(v1m, rv2); v1m = rv1; i1m = ri; }
            else v2m = fmaxf(v2m, rv1);
        }
        fidx[row0 + tid] = i1m;
        int amb = (v1m - v2m < MARGIN) ? 1 : 0;
        unsigned long long m = __ballot(amb);
        int nb = __popcll(m);
        int basep = 0;
        if (tid == 0 && nb) basep = atomicAdd(acnt, nb);
        basep = __shfl(basep, 0);
        if (amb) {
            int pfx = __popcll(m & ((1ULL << tid) - 1ULL));
            alist[basep + pfx] = (int)(row0 + tid);
        }
    }
}

// exact fp32 re-argmax for margin-ambiguous rows, 32-row groups share the e-stream
__global__ __launch_bounds__(256, 2)
void vq_refine(const float* __restrict__ z, const float* __restrict__ e,
               const float* __restrict__ e2, const int* __restrict__ acnt,
               const int* __restrict__ alist, int* __restrict__ fidx) {
    __shared__ __align__(16) float z_s[32][D];        // 32 KB
    __shared__ __align__(16) float e_s[16][NC + 4];   // 33 KB
    __shared__ int rowg[32];
    __shared__ int idx_s[32];
    const int tid = threadIdx.x, lane = tid & 63, w = tid >> 6;
    const int cnt = *acnt;
    for (int g = blockIdx.x; g * 32 < cnt; g += gridDim.x) {
        const int base = g * 32;
        __syncthreads();   // prev iteration fully done with z_s/rowg/idx_s
        if (tid < 32) rowg[tid] = alist[min(base + tid, cnt - 1)];  // pad w/ first row
        __syncthreads();
        #pragma unroll
        for (int j = 0; j < 8; ++j) {      // gather 32 z rows
            int c = j * 256 + tid, rl = c >> 6, c4 = (c & 63) * 4;
            *(float4*)&z_s[rl][c4] = *(const float4*)(z + (long)rowg[rl] * D + c4);
        }
        float acc[8][8];
        #pragma unroll
        for (int r = 0; r < 8; ++r)
            #pragma unroll
            for (int c = 0; c < 8; ++c) acc[r][c] = 0.0f;
        const int r0 = w * 8, c_lo = lane * 4;
        for (int kc = 0; kc < D; kc += 16) {
            __syncthreads();
            #pragma unroll
            for (int p = 0; p < 8; ++p) {
                int c = p * 64 + (tid >> 2), kk4 = (tid & 3) * 4;
                float4 v = *(const float4*)(e + c * D + kc + kk4);
                e_s[kk4 + 0][c] = v.x; e_s[kk4 + 1][c] = v.y;
                e_s[kk4 + 2][c] = v.z; e_s[kk4 + 3][c] = v.w;
            }
            __syncthreads();
            #pragma unroll
            for (int k4 = 0; k4 < 16; k4 += 4) {
                float zr[8][4];
                #pragma unroll
                for (int r = 0; r < 8; ++r) *(float4*)zr[r] = *(const float4*)&z_s[r0 + r][kc + k4];
                #pragma unroll
                for (int kk = 0; kk < 4; ++kk) {
                    float ev[8];
                    *(float4*)&ev[0] = *(const float4*)&e_s[k4 + kk][c_lo];
                    *(float4*)&ev[4] = *(const float4*)&e_s[k4 + kk][c_lo + 256];
                    #pragma unroll
                    for (int r = 0; r < 8; ++r)
                        #pragma unroll
                        for (int c = 0; c < 8; ++c) acc[r][c] = fmaf(zr[r][kk], ev[c], acc[r][c]);
                }
            }
        }
        float e2v[8];
        #pragma unroll
        for (int gg = 0; gg < 2; ++gg)
            #pragma unroll
            for (int i = 0; i < 4; ++i) e2v[gg * 4 + i] = e2[gg * 256 + c_lo + i];
        #pragma unroll
        for (int r = 0; r < 8; ++r) {
            float bvv = -3.0e38f; int bc = 0;
            #pragma unroll
            for (int c = 0; c < 8; ++c) {
                int col = (c >> 2) * 256 + c_lo + (c & 3);
                float v = e2v[c] - 2.0f * acc[r][c];
                if (v > bvv) { bvv = v; bc = col; }
            }
            #pragma unroll
            for (int off = 32; off; off >>= 1) {
                float ov = __shfl_xor(bvv, off); int oc = __shfl_xor(bc, off);
                if (ov > bvv || (ov == bvv && oc < bc)) { bvv = ov; bc = oc; }
            }
            if (lane == 0) idx_s[r0 + r] = bc;
        }
        __syncthreads();
        if (tid < 32 && base + tid < cnt) fidx[rowg[tid]] = idx_s[tid];
    }
}

// pure streaming epilogue: idx out + z_q_st + per-block loss partial. No atomics.
__global__ __launch_bounds__(256)
void vq_epi(const float* __restrict__ z, const float* __restrict__ e,
            const int* __restrict__ fidx, float* __restrict__ out,
            float* __restrict__ lpart) {
    __shared__ int idxs[64];
    __shared__ float rs[4];
    const int t = threadIdx.x, lane = t & 63, w = t >> 6;
    const long row0 = (long)blockIdx.x * 64;
    if (t < 64) {
        int ix = fidx[row0 + t];
        idxs[t] = ix;
        out[OFF_IDX + row0 + t] = (float)ix;
    }
    __syncthreads();
    float ls = 0.f;
    #pragma unroll 4
    for (int j = 0; j < 16; ++j) {
        const int r = w * 16 + j;
        const long row = row0 + r;
        const int idx = idxs[r];
        float4 zv = *(const float4*)(z + row * D + lane * 4);
        float4 ev = *(const float4*)(e + (long)idx * D + lane * 4);
        float4 dq;
        dq.x = ev.x - zv.x; dq.y = ev.y - zv.y; dq.z = ev.z - zv.z; dq.w = ev.w - zv.w;
        float4 o;
        o.x = zv.x + dq.x; o.y = zv.y + dq.y; o.z = zv.z + dq.z; o.w = zv.w + dq.w;
        *(float4*)(out + OFF_ZQ + row * D + lane * 4) = o;
        ls += dq.x * dq.x + dq.y * dq.y + dq.z * dq.z + dq.w * dq.w;
    }
    #pragma unroll
    for (int off = 32; off; off >>= 1) ls += __shfl_xor(ls, off);
    if (lane == 0) rs[w] = ls;
    __syncthreads();
    if (t == 0) lpart[blockIdx.x] = rs[0] + rs[1] + rs[2] + rs[3];
}

// histogram via LDS + FUSED finalization: the last block to finish publishes
// hist to out and reduces the 2048 loss partials (done-counter handshake).
__global__ __launch_bounds__(256)
void vq_hist(const int* __restrict__ fidx, const float* __restrict__ lpart,
             float* __restrict__ hist, int* __restrict__ done,
             float* __restrict__ out) {
    __shared__ int h[NC];
    __shared__ float sred[4];
    __shared__ int lastf;
    const int t = threadIdx.x, lane = t & 63, w = t >> 6;
    h[t] = 0; h[t + 256] = 0;
    __syncthreads();
    const long base = (long)blockIdx.x * 2048;
    #pragma unroll
    for (int j = 0; j < 8; ++j) {
        long i = base + j * 256 + t;
        atomicAdd(&h[fidx[i]], 1);
    }
    __syncthreads();
    #pragma unroll
    for (int j = 0; j < 2; ++j) {
        int k = j * 256 + t;
        int c = h[k];
        if (c) atomicAdd(&hist[k], (float)c);
    }
    __threadfence();                         // release our hist atomics
    if (t == 0) lastf = (atomicAdd(done, 1) == 63);
    __syncthreads();
    if (!lastf) return;
    __threadfence();                         // acquire other blocks' atomics
    // publish hist via device-scope atomic reads (cross-XCD safe)
    out[OFF_HIST + t]       = atomicAdd(&hist[t], 0.0f);
    out[OFF_HIST + 256 + t] = atomicAdd(&hist[t + 256], 0.0f);
    // reduce 2048 loss partials (written by the previous kernel: visible)
    float s = 0.f;
    #pragma unroll
    for (int j = 0; j < 8; ++j) s += lpart[j * 256 + t];
    #pragma unroll
    for (int off = 32; off; off >>= 1) s += __shfl_xor(s, off);
    if (lane == 0) sred[w] = s;
    __syncthreads();
    if (t == 0) {
        float m = (sred[0] + sred[1] + sred[2] + sred[3]) / 33554432.0f;
        out[OFF_VQ] = m;
        out[OFF_CM] = 0.25f * m;
    }
}

// ================= fallback (ws too small): round-2 fp32 path =================
__global__ __launch_bounds__(256, 2)
void vq_main_fb(const float* __restrict__ z, const float* __restrict__ e,
                const float* __restrict__ e2, float* __restrict__ out,
                float* __restrict__ ws_loss, float* __restrict__ ws_hist) {
    __shared__ __align__(16) float z_s[32][D];
    __shared__ __align__(16) float e_s[16][NC + 4];
    __shared__ int   idx_s[32];
    __shared__ float red_s[4];
    const int tid = threadIdx.x, lane = tid & 63, w = tid >> 6;
    const long row0 = (long)blockIdx.x * 32;
    {
        const float4* zg = (const float4*)(z + row0 * D);
        float4* zs = (float4*)(&z_s[0][0]);
        #pragma unroll
        for (int i = 0; i < 8; ++i) zs[i * 256 + tid] = zg[i * 256 + tid];
    }
    float acc[8][8];
    #pragma unroll
    for (int r = 0; r < 8; ++r)
        #pragma unroll
        for (int c = 0; c < 8; ++c) acc[r][c] = 0.0f;
    const int r0 = w * 8, c_lo = lane * 4;
    for (int kc = 0; kc < D; kc += 16) {
        __syncthreads();
        #pragma unroll
        for (int p = 0; p < 8; ++p) {
            int c = p * 64 + (tid >> 2), kk4 = (tid & 3) * 4;
            float4 v = *(const float4*)(e + c * D + kc + kk4);
            e_s[kk4 + 0][c] = v.x; e_s[kk4 + 1][c] = v.y;
            e_s[kk4 + 2][c] = v.z; e_s[kk4 + 3][c] = v.w;
        }
        __syncthreads();
        #pragma unroll
        for (int k4 = 0; k4 < 16; k4 += 4) {
            float zr[8][4];
            #pragma unroll
            for (int r = 0; r < 8; ++r) *(float4*)zr[r] = *(const float4*)&z_s[r0 + r][kc + k4];
            #pragma unroll
            for (int kk = 0; kk < 4; ++kk) {
                float ev[8];
                *(float4*)&ev[0] = *(const float4*)&e_s[k4 + kk][c_lo];
                *(float4*)&ev[4] = *(const float4*)&e_s[k4 + kk][c_lo + 256];
                #pragma unroll
                for (int r = 0; r < 8; ++r)
                    #pragma unroll
                    for (int c = 0; c < 8; ++c) acc[r][c] = fmaf(zr[r][kk], ev[c], acc[r][c]);
            }
        }
    }
    float e2v[8];
    #pragma unroll
    for (int g = 0; g < 2; ++g)
        #pragma unroll
        for (int i = 0; i < 4; ++i) e2v[g * 4 + i] = e2[g * 256 + c_lo + i];
    #pragma unroll
    for (int r = 0; r < 8; ++r) {
        float bvv = -3.0e38f; int bc = 0;
        #pragma unroll
        for (int c = 0; c < 8; ++c) {
            int col = (c >> 2) * 256 + c_lo + (c & 3);
            float v = e2v[c] - 2.0f * acc[r][c];
            if (v > bvv) { bvv = v; bc = col; }
        }
        #pragma unroll
        for (int off = 32; off; off >>= 1) {
            float ov = __shfl_xor(bvv, off); int oc = __shfl_xor(bc, off);
            if (ov > bvv || (ov == bvv && oc < bc)) { bvv = ov; bc = oc; }
        }
        if (lane == 0) idx_s[r] = bc;
    }
    __syncthreads();
    if (tid < 32) {
        int bc = idx_s[tid];
        out[OFF_IDX + row0 + tid] = (float)bc;
        atomicAdd(&ws_hist[bc], 1.0f);
    }
    float lsum = 0.0f;
    for (int r = 0; r < 32; ++r) {
        int idx = idx_s[r];
        float ev = e[idx * D + tid];
        float zv = z_s[r][tid];
        float dq = ev - zv;
        out[OFF_ZQ + (row0 + r) * D + tid] = zv + dq;
        lsum += dq * dq;
    }
    #pragma unroll
    for (int off = 32; off; off >>= 1) lsum += __shfl_xor(lsum, off);
    if (lane == 0) red_s[w] = lsum;
    __syncthreads();
    if (tid == 0) atomicAdd(ws_loss, red_s[0] + red_s[1] + red_s[2] + red_s[3]);
}

__global__ void vq_init_fb(float* __restrict__ ws) {
    int t = threadIdx.x;
    if (t < 513) ws[t] = 0.0f;
}
__global__ void vq_fin_fb(const float* __restrict__ ws, float* __restrict__ out) {
    int t = blockIdx.x * blockDim.x + threadIdx.x;
    if (t < NC) out[OFF_HIST + t] = ws[1 + t];
    if (t == NC) {
        float m = ws[0] / 33554432.0f;
        out[OFF_VQ] = m; out[OFF_CM] = 0.25f * m;
    }
}

extern "C" void kernel_launch(void* const* d_in, const int* in_sizes, int n_in,
                              void* d_out, int out_size, void* d_ws, size_t ws_size,
                              hipStream_t stream) {
    const float* z = (const float*)d_in[0];
    const float* e = (const float*)d_in[1];
    float* out = (float*)d_out;
    float* ws  = (float*)d_ws;

    if (ws_size >= (size_t)WS_NEED) {
        float* lpart = ws + WS_LPART;
        float* hist  = ws + WS_HIST;
        float* e2    = ws + WS_E2;
        int*   acnt  = (int*)(ws + WS_CNT);
        int*   done  = (int*)(ws + WS_DONE);
        int*   alist = (int*)(ws + WS_AMB);
        int*   fidx  = (int*)(ws + WS_FIDX);
        unsigned short* Bk = (unsigned short*)(ws + WS_BK);

        vq_convB<<<NC, 256, 0, stream>>>(e, Bk, e2, hist, acnt, done);
        vq_gemm<<<2048, 512, 0, stream>>>(z, Bk, e2, fidx, acnt, alist);
        vq_refine<<<512, 256, 0, stream>>>(z, e, e2, acnt, alist, fidx);
        vq_epi<<<2048, 256, 0, stream>>>(z, e, fidx, out, lpart);
        vq_hist<<<64, 256, 0, stream>>>(fidx, lpart, hist, done, out);
    } else {
        float* ws_loss = ws;
        float* ws_hist = ws + 1;
        float* ws_e2   = ws + 513;
        vq_init_fb<<<1, 1024, 0, stream>>>(ws);
        vq_e2<<<NC, 64, 0, stream>>>(e, ws_e2);
        vq_main_fb<<<4096, 256, 0, stream>>>(z, e, ws_e2, out, ws_loss, ws_hist);
        vq_fin_fb<<<3, 256, 0, stream>>>(ws, out);
    }
}

// Round 7
// 378.027 us; speedup vs baseline: 1.1699x; 1.1699x over previous
//
#include <hip/hip_runtime.h>
#include <hip/hip_bf16.h>

#define D 256
#define NC 512
#define NROWS 131072L

// out layout (fp32 elements), reference return order
#define OFF_ZQ   0L
#define OFF_VQ   33554432L
#define OFF_CM   33554433L
#define OFF_IDX  33554434L
#define OFF_HIST 33685506L

// ws float offsets
#define WS_LPART 0        // [0, 2048)       per-block loss partials (unambiguous rows)
#define WS_HIST  2048     // [2048, 2560)
#define WS_E2    2560     // [2560, 3072)
#define WS_CNT   3072     // ambig count (int)
#define WS_DONE  3073     // histfin done-counter (int)
#define WS_LCORR 3074     // ambiguous-row loss sum (float, atomic)
#define WS_AMB   3136     // [3136, 134208)   ambig row list (int)
#define WS_FIDX  134208   // [134208, 265280) final idx (int)
#define WS_BK    265280   // bf16 eh, k-slab-major: 8 slabs x 512 codes x 32 k
#define WS_NEED  (330816L * 4)

#define MARGIN 0.75f

typedef __attribute__((ext_vector_type(8))) short bf16x8;
typedef __attribute__((ext_vector_type(4))) float f32x4;

__device__ __forceinline__ unsigned short f2bf(float f) {
    union { float f; unsigned int u; } a; a.f = f;
    return (unsigned short)((a.u + 0x7FFFu + ((a.u >> 16) & 1u)) >> 16);  // RNE
}

// kept for fallback path
__global__ void vq_e2(const float* __restrict__ e, float* __restrict__ e2) {
    int c = blockIdx.x;
    int l = threadIdx.x;  // 64
    float4 v = *(const float4*)(e + c * D + l * 4);
    float s = v.x * v.x + v.y * v.y + v.z * v.z + v.w * v.w;
    #pragma unroll
    for (int off = 32; off; off >>= 1) s += __shfl_xor(s, off);
    if (l == 0) e2[c] = s;
}

// Bk[slab][code][32] = bf16(e[code][slab*32..+32)) + fused e2 + ws zeroing
__global__ void vq_convB(const float* __restrict__ e, unsigned short* __restrict__ Bk,
                         float* __restrict__ e2, float* __restrict__ hist,
                         int* __restrict__ acnt, int* __restrict__ done,
                         float* __restrict__ lcorr) {
    __shared__ float r4[4];
    int code = blockIdx.x, k = threadIdx.x;   // 512 blocks x 256 threads
    float v = e[code * D + k];
    Bk[((k >> 5) * NC + code) * 32 + (k & 31)] = f2bf(v);
    float s = v * v;
    #pragma unroll
    for (int off = 32; off; off >>= 1) s += __shfl_xor(s, off);
    if ((k & 63) == 0) r4[k >> 6] = s;
    if (k == 0) {
        hist[code] = 0.0f;                    // zero hist bin owned by this block
        if (code == 0) { *acnt = 0; *done = 0; *lcorr = 0.0f; }
    }
    __syncthreads();
    if (k == 0) e2[code] = r4[0] + r4[1] + r4[2] + r4[3];
}

// MEGA: R1 gemm core (64x512 tile, 8 waves 1(M)x8(N), z staged in LDS, B direct
// from L2) + cheap value-only top-2 + fused streaming epilogue (z_q write, loss
// over unambiguous rows). NO global hist atomics, NO idx writes here.
__global__ __launch_bounds__(512, 4)
void vq_gemm(const float* __restrict__ z, const unsigned short* __restrict__ Bk,
             const float* __restrict__ e2, const float* __restrict__ e,
             int* __restrict__ fidx, int* __restrict__ acnt, int* __restrict__ alist,
             float* __restrict__ lpart, float* __restrict__ out) {
    __shared__ __align__(16) unsigned short zh[64 * 264];   // 33 KB, +8 pad
    __shared__ float red[64 * 25];                          // 6.25 KB
    __shared__ int idx_s[64];                               // idx | (amb<<16)
    __shared__ float rs[8];

    const int tid = threadIdx.x;
    const int w = tid >> 6, l = tid & 63, q = l >> 4, ln = l & 15;
    const long row0 = (long)blockIdx.x * 64;

    // ---- stage z once: 64 rows x 256 f32 -> bf16 hi, padded LDS ----
    #pragma unroll
    for (int j = 0; j < 8; ++j) {
        int c = j * 512 + tid;              // float4 chunk 0..4095
        int row = c >> 6, c4 = (c & 63) * 4;
        float4 av = *(const float4*)(z + (row0 + row) * D + c4);
        *(ushort4*)&zh[row * 264 + c4] =
            make_ushort4(f2bf(av.x), f2bf(av.y), f2bf(av.z), f2bf(av.w));
    }
    __syncthreads();

    // per-lane invariant bases (R1 structure)
    const unsigned short* bbase = Bk + ((w * 64 + ln) * 32 + q * 8);
    const unsigned short* abase = &zh[ln * 264 + q * 8];

    f32x4 acc[4][4];                        // [mt][nt]
    #pragma unroll
    for (int mt = 0; mt < 4; ++mt)
        #pragma unroll
        for (int nt = 0; nt < 4; ++nt) acc[mt][nt] = (f32x4){0.f, 0.f, 0.f, 0.f};

    #pragma unroll
    for (int s = 0; s < 8; ++s) {
        const unsigned short* bs = bbase + s * (NC * 32);
        bf16x8 bfr[4], af[4];
        #pragma unroll
        for (int nt = 0; nt < 4; ++nt)       // coalesced 1KB/wave, L2-hit
            bfr[nt] = *(const bf16x8*)(bs + nt * (16 * 32));
        #pragma unroll
        for (int mt = 0; mt < 4; ++mt)
            af[mt] = *(const bf16x8*)(abase + mt * (16 * 264) + s * 32);
        #pragma unroll
        for (int mt = 0; mt < 4; ++mt)
            #pragma unroll
            for (int nt = 0; nt < 4; ++nt)
                acc[mt][nt] = __builtin_amdgcn_mfma_f32_16x16x32_bf16(af[mt], bfr[nt], acc[mt][nt], 0, 0, 0);
    }

    // ---- per-row top-2, value-only (ties => gap 0 => ambiguous => refined) ----
    float e2v[4];
    #pragma unroll
    for (int nt = 0; nt < 4; ++nt) e2v[nt] = e2[w * 64 + nt * 16 + ln];

    #pragma unroll
    for (int mt = 0; mt < 4; ++mt) {
        #pragma unroll
        for (int r = 0; r < 4; ++r) {
            float v1 = -3.0e38f, v2 = -3.0e38f; int i1 = 0;
            #pragma unroll
            for (int nt = 0; nt < 4; ++nt) {
                float v = fmaf(-2.0f, acc[mt][nt][r], e2v[nt]);
                int c = w * 64 + nt * 16 + ln;
                if (v > v1) { v2 = v1; v1 = v; i1 = c; }
                else v2 = fmaxf(v2, v);
            }
            float v1p = v1;
            #pragma unroll
            for (int off = 1; off < 16; off <<= 1) {   // (v1,v2)-only butterfly
                float ov1 = __shfl_xor(v1, off);
                float ov2 = __shfl_xor(v2, off);
                v2 = fmaxf(fmaxf(v2, ov2), fminf(v1, ov1));
                v1 = fmaxf(v1, ov1);
            }
            unsigned long long mm = __ballot(v1p == v1);
            unsigned int gm = (unsigned int)((mm >> (q * 16)) & 0xFFFFULL);
            int src = (q << 4) + (__ffs(gm) - 1);
            i1 = __shfl(i1, src);
            if (ln == 0) {
                int rr = mt * 16 + q * 4 + r;          // block-local row
                red[rr * 25 + w * 3 + 0] = v1;
                red[rr * 25 + w * 3 + 1] = (float)i1;
                red[rr * 25 + w * 3 + 2] = v2;
            }
        }
    }
    __syncthreads();
    // ---- 8-way col-group merge; fidx + wave-aggregated ambiguous append ----
    if (tid < 64) {
        float v1m = -3.0e38f, v2m = -3.0e38f; int i1m = 0;
        #pragma unroll
        for (int g = 0; g < 8; ++g) {
            float rv1 = red[tid * 25 + g * 3 + 0];
            int   ri  = (int)red[tid * 25 + g * 3 + 1];
            float rv2 = red[tid * 25 + g * 3 + 2];
            if (rv1 > v1m) { v2m = fmaxf(v1m, rv2); v1m = rv1; i1m = ri; }
            else v2m = fmaxf(v2m, rv1);
        }
        int amb = (v1m - v2m < MARGIN) ? 1 : 0;
        idx_s[tid] = i1m | (amb << 16);
        fidx[row0 + tid] = i1m;
        unsigned long long m = __ballot(amb);
        int nb = __popcll(m);
        int basep = 0;
        if (tid == 0 && nb) basep = atomicAdd(acnt, nb);
        basep = __shfl(basep, 0);
        if (amb) {
            int pfx = __popcll(m & ((1ULL << tid) - 1ULL));
            alist[basep + pfx] = (int)(row0 + tid);
        }
    }
    __syncthreads();

    // ---- fused streaming epilogue: z_q for all rows (z is L2/L3-warm),
    //      loss for unambiguous rows only (refine adds ambiguous exactly) ----
    float ls = 0.f;
    #pragma unroll
    for (int j = 0; j < 8; ++j) {
        const int r = w * 8 + j;
        const long row = row0 + r;
        const int v = idx_s[r];
        const int idx = v & 0xFFFF;
        float4 zv = *(const float4*)(z + row * D + l * 4);
        float4 ev = *(const float4*)(e + (long)idx * D + l * 4);
        float4 dq;
        dq.x = ev.x - zv.x; dq.y = ev.y - zv.y; dq.z = ev.z - zv.z; dq.w = ev.w - zv.w;
        float4 o;
        o.x = zv.x + dq.x; o.y = zv.y + dq.y; o.z = zv.z + dq.z; o.w = zv.w + dq.w;
        *(float4*)(out + OFF_ZQ + row * D + l * 4) = o;
        if (!(v >> 16))
            ls += dq.x * dq.x + dq.y * dq.y + dq.z * dq.z + dq.w * dq.w;
    }
    #pragma unroll
    for (int off = 32; off; off >>= 1) ls += __shfl_xor(ls, off);
    if (l == 0) rs[w] = ls;
    __syncthreads();
    if (tid == 0) {
        float t = 0.f;
        #pragma unroll
        for (int i = 0; i < 8; ++i) t += rs[i];
        lpart[blockIdx.x] = t;
    }
}

// exact fp32 re-argmax for margin-ambiguous rows; updates fidx, patches z_q
// where the choice changed, adds the ambiguous rows' exact loss terms to lcorr.
__global__ __launch_bounds__(256, 2)
void vq_refine(const float* __restrict__ z, const float* __restrict__ e,
               const float* __restrict__ e2, const int* __restrict__ acnt,
               const int* __restrict__ alist, int* __restrict__ fidx,
               float* __restrict__ lcorr, float* __restrict__ out) {
    __shared__ __align__(16) float z_s[32][D];        // 32 KB
    __shared__ __align__(16) float e_s[16][NC + 4];   // 33 KB
    __shared__ int rowg[32];
    __shared__ int idx_s[32];
    __shared__ float rs2[4];
    const int tid = threadIdx.x, lane = tid & 63, w = tid >> 6;
    const int cnt = *acnt;
    for (int g = blockIdx.x; g * 32 < cnt; g += gridDim.x) {
        const int base = g * 32;
        __syncthreads();   // prev iteration fully done with z_s/rowg/idx_s
        if (tid < 32) rowg[tid] = alist[min(base + tid, cnt - 1)];  // pad w/ first row
        __syncthreads();
        #pragma unroll
        for (int j = 0; j < 8; ++j) {      // gather 32 z rows
            int c = j * 256 + tid, rl = c >> 6, c4 = (c & 63) * 4;
            *(float4*)&z_s[rl][c4] = *(const float4*)(z + (long)rowg[rl] * D + c4);
        }
        float acc[8][8];
        #pragma unroll
        for (int r = 0; r < 8; ++r)
            #pragma unroll
            for (int c = 0; c < 8; ++c) acc[r][c] = 0.0f;
        const int r0 = w * 8, c_lo = lane * 4;
        for (int kc = 0; kc < D; kc += 16) {
            __syncthreads();
            #pragma unroll
            for (int p = 0; p < 8; ++p) {
                int c = p * 64 + (tid >> 2), kk4 = (tid & 3) * 4;
                float4 v = *(const float4*)(e + c * D + kc + kk4);
                e_s[kk4 + 0][c] = v.x; e_s[kk4 + 1][c] = v.y;
                e_s[kk4 + 2][c] = v.z; e_s[kk4 + 3][c] = v.w;
            }
            __syncthreads();
            #pragma unroll
            for (int k4 = 0; k4 < 16; k4 += 4) {
                float zr[8][4];
                #pragma unroll
                for (int r = 0; r < 8; ++r) *(float4*)zr[r] = *(const float4*)&z_s[r0 + r][kc + k4];
                #pragma unroll
                for (int kk = 0; kk < 4; ++kk) {
                    float ev[8];
                    *(float4*)&ev[0] = *(const float4*)&e_s[k4 + kk][c_lo];
                    *(float4*)&ev[4] = *(const float4*)&e_s[k4 + kk][c_lo + 256];
                    #pragma unroll
                    for (int r = 0; r < 8; ++r)
                        #pragma unroll
                        for (int c = 0; c < 8; ++c) acc[r][c] = fmaf(zr[r][kk], ev[c], acc[r][c]);
                }
            }
        }
        float e2v[8];
        #pragma unroll
        for (int gg = 0; gg < 2; ++gg)
            #pragma unroll
            for (int i = 0; i < 4; ++i) e2v[gg * 4 + i] = e2[gg * 256 + c_lo + i];
        #pragma unroll
        for (int r = 0; r < 8; ++r) {
            float bvv = -3.0e38f; int bc = 0;
            #pragma unroll
            for (int c = 0; c < 8; ++c) {
                int col = (c >> 2) * 256 + c_lo + (c & 3);
                float v = e2v[c] - 2.0f * acc[r][c];
                if (v > bvv) { bvv = v; bc = col; }
            }
            #pragma unroll
            for (int off = 32; off; off >>= 1) {
                float ov = __shfl_xor(bvv, off); int oc = __shfl_xor(bc, off);
                if (ov > bvv || (ov == bvv && oc < bc)) { bvv = ov; bc = oc; }
            }
            if (lane == 0) idx_s[r0 + r] = bc;
        }
        __syncthreads();
        // ---- exact loss for valid ambiguous rows; patch z_q if idx changed ----
        float ls = 0.f;
        #pragma unroll
        for (int j = 0; j < 8; ++j) {
            const int r = w * 8 + j;
            const bool valid = (base + r < cnt);
            const int row = rowg[r];
            const int nb = idx_s[r];
            float4 zv = *(const float4*)&z_s[r][lane * 4];
            float4 ev = *(const float4*)(e + (long)nb * D + lane * 4);
            float4 dq;
            dq.x = ev.x - zv.x; dq.y = ev.y - zv.y; dq.z = ev.z - zv.z; dq.w = ev.w - zv.w;
            if (valid)
                ls += dq.x * dq.x + dq.y * dq.y + dq.z * dq.z + dq.w * dq.w;
            const int ob = fidx[row];
            if (valid && nb != ob) {
                float4 o;
                o.x = zv.x + dq.x; o.y = zv.y + dq.y; o.z = zv.z + dq.z; o.w = zv.w + dq.w;
                *(float4*)(out + OFF_ZQ + (long)row * D + lane * 4) = o;
            }
        }
        #pragma unroll
        for (int off = 32; off; off >>= 1) ls += __shfl_xor(ls, off);
        if (lane == 0) rs2[w] = ls;
        __syncthreads();   // all ob reads done before fidx update
        if (tid == 0) atomicAdd(lcorr, rs2[0] + rs2[1] + rs2[2] + rs2[3]);
        if (tid < 32 && base + tid < cnt) fidx[rowg[tid]] = idx_s[tid];
    }
}

// FINAL: idx out + LDS histogram + done-counter; last block publishes hist and
// reduces loss partials + lcorr into vq/cm.
__global__ __launch_bounds__(256)
void vq_histfin(const int* __restrict__ fidx, const float* __restrict__ lpart,
                const float* __restrict__ lcorr, float* __restrict__ hist,
                int* __restrict__ done, float* __restrict__ out) {
    __shared__ int h[NC];
    __shared__ float sred[4];
    __shared__ int lastf;
    const int t = threadIdx.x, lane = t & 63, w = t >> 6;
    h[t] = 0; h[t + 256] = 0;
    __syncthreads();
    const long base = (long)blockIdx.x * 2048;
    #pragma unroll
    for (int j = 0; j < 8; ++j) {
        long i = base + j * 256 + t;
        int idx = fidx[i];
        out[OFF_IDX + i] = (float)idx;
        atomicAdd(&h[idx], 1);
    }
    __syncthreads();
    #pragma unroll
    for (int j = 0; j < 2; ++j) {
        int k = j * 256 + t;
        int c = h[k];
        if (c) atomicAdd(&hist[k], (float)c);
    }
    __threadfence();                         // release our hist atomics
    if (t == 0) lastf = (atomicAdd(done, 1) == 63);
    __syncthreads();
    if (!lastf) return;
    __threadfence();                         // acquire other blocks' atomics
    out[OFF_HIST + t]       = atomicAdd(&hist[t], 0.0f);
    out[OFF_HIST + 256 + t] = atomicAdd(&hist[t + 256], 0.0f);
    float s = 0.f;
    #pragma unroll
    for (int j = 0; j < 8; ++j) s += lpart[j * 256 + t];
    #pragma unroll
    for (int off = 32; off; off >>= 1) s += __shfl_xor(s, off);
    if (lane == 0) sred[w] = s;
    __syncthreads();
    if (t == 0) {
        float tot = sred[0] + sred[1] + sred[2] + sred[3] + *lcorr;
        float m = tot / 33554432.0f;         // mean((z_q - z)^2)
        out[OFF_VQ] = m;
        out[OFF_CM] = 0.25f * m;
    }
}

// ================= fallback (ws too small): round-2 fp32 path =================
__global__ __launch_bounds__(256, 2)
void vq_main_fb(const float* __restrict__ z, const float* __restrict__ e,
                const float* __restrict__ e2, float* __restrict__ out,
                float* __restrict__ ws_loss, float* __restrict__ ws_hist) {
    __shared__ __align__(16) float z_s[32][D];
    __shared__ __align__(16) float e_s[16][NC + 4];
    __shared__ int   idx_s[32];
    __shared__ float red_s[4];
    const int tid = threadIdx.x, lane = tid & 63, w = tid >> 6;
    const long row0 = (long)blockIdx.x * 32;
    {
        const float4* zg = (const float4*)(z + row0 * D);
        float4* zs = (float4*)(&z_s[0][0]);
        #pragma unroll
        for (int i = 0; i < 8; ++i) zs[i * 256 + tid] = zg[i * 256 + tid];
    }
    float acc[8][8];
    #pragma unroll
    for (int r = 0; r < 8; ++r)
        #pragma unroll
        for (int c = 0; c < 8; ++c) acc[r][c] = 0.0f;
    const int r0 = w * 8, c_lo = lane * 4;
    for (int kc = 0; kc < D; kc += 16) {
        __syncthreads();
        #pragma unroll
        for (int p = 0; p < 8; ++p) {
            int c = p * 64 + (tid >> 2), kk4 = (tid & 3) * 4;
            float4 v = *(const float4*)(e + c * D + kc + kk4);
            e_s[kk4 + 0][c] = v.x; e_s[kk4 + 1][c] = v.y;
            e_s[kk4 + 2][c] = v.z; e_s[kk4 + 3][c] = v.w;
        }
        __syncthreads();
        #pragma unroll
        for (int k4 = 0; k4 < 16; k4 += 4) {
            float zr[8][4];
            #pragma unroll
            for (int r = 0; r < 8; ++r) *(float4*)zr[r] = *(const float4*)&z_s[r0 + r][kc + k4];
            #pragma unroll
            for (int kk = 0; kk < 4; ++kk) {
                float ev[8];
                *(float4*)&ev[0] = *(const float4*)&e_s[k4 + kk][c_lo];
                *(float4*)&ev[4] = *(const float4*)&e_s[k4 + kk][c_lo + 256];
                #pragma unroll
                for (int r = 0; r < 8; ++r)
                    #pragma unroll
                    for (int c = 0; c < 8; ++c) acc[r][c] = fmaf(zr[r][kk], ev[c], acc[r][c]);
            }
        }
    }
    float e2v[8];
    #pragma unroll
    for (int g = 0; g < 2; ++g)
        #pragma unroll
        for (int i = 0; i < 4; ++i) e2v[g * 4 + i] = e2[g * 256 + c_lo + i];
    #pragma unroll
    for (int r = 0; r < 8; ++r) {
        float bvv = -3.0e38f; int bc = 0;
        #pragma unroll
        for (int c = 0; c < 8; ++c) {
            int col = (c >> 2) * 256 + c_lo + (c & 3);
            float v = e2v[c] - 2.0f * acc[r][c];
            if (v > bvv) { bvv = v; bc = col; }
        }
        #pragma unroll
        for (int off = 32; off; off >>= 1) {
            float ov = __shfl_xor(bvv, off); int oc = __shfl_xor(bc, off);
            if (ov > bvv || (ov == bvv && oc < bc)) { bvv = ov; bc = oc; }
        }
        if (lane == 0) idx_s[r] = bc;
    }
    __syncthreads();
    if (tid < 32) {
        int bc = idx_s[tid];
        out[OFF_IDX + row0 + tid] = (float)bc;
        atomicAdd(&ws_hist[bc], 1.0f);
    }
    float lsum = 0.0f;
    for (int r = 0; r < 32; ++r) {
        int idx = idx_s[r];
        float ev = e[idx * D + tid];
        float zv = z_s[r][tid];
        float dq = ev - zv;
        out[OFF_ZQ + (row0 + r) * D + tid] = zv + dq;
        lsum += dq * dq;
    }
    #pragma unroll
    for (int off = 32; off; off >>= 1) lsum += __shfl_xor(lsum, off);
    if (lane == 0) red_s[w] = lsum;
    __syncthreads();
    if (tid == 0) atomicAdd(ws_loss, red_s[0] + red_s[1] + red_s[2] + red_s[3]);
}

__global__ void vq_init_fb(float* __restrict__ ws) {
    int t = threadIdx.x;
    if (t < 513) ws[t] = 0.0f;
}
__global__ void vq_fin_fb(const float* __restrict__ ws, float* __restrict__ out) {
    int t = blockIdx.x * blockDim.x + threadIdx.x;
    if (t < NC) out[OFF_HIST + t] = ws[1 + t];
    if (t == NC) {
        float m = ws[0] / 33554432.0f;
        out[OFF_VQ] = m; out[OFF_CM] = 0.25f * m;
    }
}

extern "C" void kernel_launch(void* const* d_in, const int* in_sizes, int n_in,
                              void* d_out, int out_size, void* d_ws, size_t ws_size,
                              hipStream_t stream) {
    const float* z = (const float*)d_in[0];
    const float* e = (const float*)d_in[1];
    float* out = (float*)d_out;
    float* ws  = (float*)d_ws;

    if (ws_size >= (size_t)WS_NEED) {
        float* lpart = ws + WS_LPART;
        float* hist  = ws + WS_HIST;
        float* e2    = ws + WS_E2;
        int*   acnt  = (int*)(ws + WS_CNT);
        int*   done  = (int*)(ws + WS_DONE);
        float* lcorr = ws + WS_LCORR;
        int*   alist = (int*)(ws + WS_AMB);
        int*   fidx  = (int*)(ws + WS_FIDX);
        unsigned short* Bk = (unsigned short*)(ws + WS_BK);

        vq_convB<<<NC, 256, 0, stream>>>(e, Bk, e2, hist, acnt, done, lcorr);
        vq_gemm<<<2048, 512, 0, stream>>>(z, Bk, e2, e, fidx, acnt, alist, lpart, out);
        vq_refine<<<512, 256, 0, stream>>>(z, e, e2, acnt, alist, fidx, lcorr, out);
        vq_histfin<<<64, 256, 0, stream>>>(fidx, lpart, lcorr, hist, done, out);
    } else {
        float* ws_loss = ws;
        float* ws_hist = ws + 1;
        float* ws_e2   = ws + 513;
        vq_init_fb<<<1, 1024, 0, stream>>>(ws);
        vq_e2<<<NC, 64, 0, stream>>>(e, ws_e2);
        vq_main_fb<<<4096, 256, 0, stream>>>(z, e, ws_e2, out, ws_loss, ws_hist);
        vq_fin_fb<<<3, 256, 0, stream>>>(ws, out);
    }
}